// Round 2
// baseline (287.615 us; speedup 1.0000x reference)
//
#include <hip/hip_runtime.h>
#include <math.h>

// ---------------- problem constants ----------------
#define BATCH 16
#define IH 384
#define IW 512
#define C1 10
#define P1H 191   // pooled H after conv1(382) / 2
#define P1W 255   // pooled W after conv1(510) / 2
#define C2 16
#define H2 189
#define W2 253
#define C3 32
#define H3 187
#define W3 251
#define N3 (H3*W3)        // 46937
#define KP 128
#define CAP 7680          // max candidates kept for NMS (LDS-resident)
#define NEGV (-1e30f)

typedef _Float16 f16x8 __attribute__((ext_vector_type(8)));
typedef _Float16 f16x4 __attribute__((ext_vector_type(4)));
typedef float    f32x16 __attribute__((ext_vector_type(16)));

#define PXT 98            // staged px per block: 96 computed + 2 halo
#define NSUB 3            // 3 x 32-px MFMA sub-tiles per wave

// ------------- kernel 1: conv1(3->10,3x3) + PReLU + maxpool2 -------------
// block (0,0,0) additionally pre-splits conv3 weights into f16 hi/lo planes
// (layout [tap][kgroup][oc][8ic]) -- saves a separate dispatch.
__global__ __launch_bounds__(256, 2) void k_conv1pool(
        const float* __restrict__ im, const float* __restrict__ w,
        const float* __restrict__ bia, const float* __restrict__ slope,
        float* __restrict__ outp,
        const float* __restrict__ w3, _Float16* __restrict__ wbuf) {
    if (blockIdx.x == 0 && blockIdx.y == 0 && blockIdx.z == 0) {
        int tid = threadIdx.y * 16 + threadIdx.x;
        for (int e = tid; e < 4608; e += 256) {
            int oc = e / 144;
            int rem = e - oc * 144;
            int ic = rem / 9;
            int tap = rem - ic * 9;
            float v = w3[e];                   // [oc][ic][ky][kx] natural order
            _Float16 h = (_Float16)v;
            _Float16 l = (_Float16)(v - (float)h);
            int d = ((tap * 2 + (ic >> 3)) * 32 + oc) * 8 + (ic & 7);
            wbuf[d] = h;
            wbuf[4608 + d] = l;
        }
    }

    int x = blockIdx.x * 16 + threadIdx.x;
    int y = blockIdx.y * 16 + threadIdx.y;
    int bb = blockIdx.z;
    if (x >= P1W || y >= P1H) return;

    float in[3][4][4];
    #pragma unroll
    for (int ci = 0; ci < 3; ++ci) {
        const float* p = im + (((size_t)bb * 3 + ci) * IH + 2 * y) * IW + 2 * x;
        #pragma unroll
        for (int r = 0; r < 4; ++r) {
            const float2* q = (const float2*)(p + (size_t)r * IW);
            float2 a0 = q[0], a1 = q[1];
            in[ci][r][0] = a0.x; in[ci][r][1] = a0.y;
            in[ci][r][2] = a1.x; in[ci][r][3] = a1.y;
        }
    }
    #pragma unroll
    for (int ci = 0; ci < 3; ++ci)
        #pragma unroll
        for (int r = 0; r < 4; ++r)
            #pragma unroll
            for (int c = 0; c < 4; ++c)
                in[ci][r][c] = (in[ci][r][c] - 127.5f) * 0.0078125f;

    #pragma unroll
    for (int oc = 0; oc < C1; ++oc) {
        const float* wo = w + oc * 27;
        float bv = bia[oc], sv = slope[oc];
        float best = -INFINITY;
        #pragma unroll
        for (int py = 0; py < 2; ++py)
            #pragma unroll
            for (int px = 0; px < 2; ++px) {
                float acc = bv;
                #pragma unroll
                for (int ci = 0; ci < 3; ++ci)
                    #pragma unroll
                    for (int ky = 0; ky < 3; ++ky)
                        #pragma unroll
                        for (int kx = 0; kx < 3; ++kx)
                            acc += in[ci][py + ky][px + kx] * wo[(ci * 3 + ky) * 3 + kx];
                float v = acc > 0.f ? acc : sv * acc;
                best = fmaxf(best, v);
            }
        outp[(((size_t)bb * C1 + oc) * P1H + y) * P1W + x] = best;
    }
}

// ------------- kernel 2: conv2(10->16,3x3) + PReLU, NHWC output -------------
// Per-thread NHWC data (2px x 16ch = 128B contiguous per thread) is re-staged
// through a 32KB XOR-swizzled LDS buffer so global stores are fully coalesced
// float4s (previous direct stores were 16B at 128B lane-stride = 8x transactions).
// Swizzle phys = g ^ ((g>>3)&7) is conflict-free on both write and read sides.
__global__ __launch_bounds__(256, 2) void k_conv2(
        const float* __restrict__ inp, const float* __restrict__ w,
        const float* __restrict__ bia, const float* __restrict__ slope,
        float* __restrict__ outp) {
    __shared__ float4 sbuf[2048];          // [4 rows][128 px][4 c4] granules
    int tx = threadIdx.x, ty = threadIdx.y;
    int tid = ty * 64 + tx;
    int x0 = blockIdx.x * 128 + tx * 2;
    int y  = blockIdx.y * 4 + ty;
    int bb = blockIdx.z;
    bool alive = (x0 < W2) && (y < H2);

    float a0[C2], a1[C2];
    #pragma unroll
    for (int oc = 0; oc < C2; ++oc) { a0[oc] = bia[oc]; a1[oc] = bia[oc]; }

    if (alive) {
        bool tail = (x0 + 3 > P1W - 1);
        for (int ci = 0; ci < C1; ++ci) {
            const float* p = inp + (((size_t)bb * C1 + ci) * P1H + y) * P1W + x0;
            float v[3][4];
            #pragma unroll
            for (int r = 0; r < 3; ++r) {
                const float* pr = p + (size_t)r * P1W;
                v[r][0] = pr[0]; v[r][1] = pr[1]; v[r][2] = pr[2];
                v[r][3] = tail ? 0.f : pr[3];
            }
            const float* wc = w + ci * 9;
            #pragma unroll
            for (int oc = 0; oc < C2; ++oc) {
                const float* wo = wc + oc * (C1 * 9);
                float s0 = a0[oc], s1 = a1[oc];
                #pragma unroll
                for (int ky = 0; ky < 3; ++ky)
                    #pragma unroll
                    for (int kx = 0; kx < 3; ++kx) {
                        float wv = wo[ky * 3 + kx];
                        s0 += v[ky][kx]     * wv;
                        s1 += v[ky][kx + 1] * wv;
                    }
                a0[oc] = s0; a1[oc] = s1;
            }
        }
        #pragma unroll
        for (int oc = 0; oc < C2; ++oc) {
            float sl = slope[oc];
            float u0 = a0[oc]; a0[oc] = u0 > 0.f ? u0 : sl * u0;
            float u1 = a1[oc]; a1[oc] = u1 > 0.f ? u1 : sl * u1;
        }
    }

    // stage to LDS (swizzled, conflict-free: 8 consecutive lanes hit 8 groups)
    #pragma unroll
    for (int c4 = 0; c4 < 4; ++c4) {
        int g0 = tid * 8 + c4;
        int p0 = g0 ^ ((g0 >> 3) & 7);
        sbuf[p0] = make_float4(a0[c4 * 4], a0[c4 * 4 + 1], a0[c4 * 4 + 2], a0[c4 * 4 + 3]);
        int g1 = tid * 8 + 4 + c4;
        int p1 = g1 ^ ((g1 >> 3) & 7);
        sbuf[p1] = make_float4(a1[c4 * 4], a1[c4 * 4 + 1], a1[c4 * 4 + 2], a1[c4 * 4 + 3]);
    }
    __syncthreads();

    // coalesced copy-out: consecutive lanes -> consecutive float4s
    const size_t obase = (size_t)bb * H2 * W2 * C2;
    #pragma unroll
    for (int it = 0; it < 8; ++it) {
        int g = it * 256 + tid;
        int c4 = g & 3, px = (g >> 2) & 127, ry = g >> 9;
        int xg = blockIdx.x * 128 + px, yg = blockIdx.y * 4 + ry;
        if (xg < W2 && yg < H2) {
            int phys = g ^ ((g >> 3) & 7);
            *(float4*)(outp + obase + ((size_t)yg * W2 + xg) * C2 + c4 * 4) = sbuf[phys];
        }
    }
}

// ------------- kernel 3: conv3 via MFMA (f16x2 split) + heads -------------
// Changes vs prev round:
//  * A staged as [row][kgroup][px] 16B granules -> fragment reads are
//    contiguous-in-lane (8 lanes = 128B line = all 32 banks) -> conflict-free.
//  * Weight fragments loaded per-tap from GLOBAL (18KB total, L1-resident)
//    instead of an 18KB LDS buffer -> LDS 57KB -> 38.7KB -> 4 blocks/CU.
__global__ __launch_bounds__(256, 4) void k_conv3mfma(
        const float* __restrict__ act,            // conv2 output, NHWC
        const _Float16* __restrict__ wbuf,        // pre-split weights hi|lo
        const float* __restrict__ b3, const float* __restrict__ s3,
        const float* __restrict__ w41, const float* __restrict__ b41,
        const float* __restrict__ w42, const float* __restrict__ b42,
        float* __restrict__ scores, float4* __restrict__ regf) {
    __shared__ __align__(16) _Float16 Ah[6 * 2 * PXT * 8];  // 18816 B
    __shared__ __align__(16) _Float16 Al[6 * 2 * PXT * 8];  // 18816 B
    __shared__ __align__(16) float    htab[32 * 8];          // 1024 B (38.7KB tot)

    int tid = threadIdx.x;
    int bx = blockIdx.x * (NSUB * 32);
    int by = blockIdx.y * 4;
    int bb = blockIdx.z;

    // -- stage per-oc head table: b3, s3, w41[0], w41[1], w42[0..3] --
    {
        int oc = tid >> 3, f = tid & 7;
        float v;
        if      (f == 0) v = b3[oc];
        else if (f == 1) v = s3[oc];
        else if (f == 2) v = w41[oc];
        else if (f == 3) v = w41[32 + oc];
        else             v = w42[(f - 4) * 32 + oc];
        htab[tid] = v;
    }
    // -- stage activations: NHWC global -> LDS [row][kg][px] granules, hi/lo --
    {
        const float* actb = act + (size_t)bb * H2 * W2 * C2;
        for (int e = tid; e < 6 * PXT * 4; e += 256) {
            int ic4 = e & 3;
            int t = e >> 2;
            int px = t % PXT;
            int row = t / PXT;
            int yg = by + row, xg = bx + px;
            float4 v = make_float4(0.f, 0.f, 0.f, 0.f);
            if (yg < H2 && xg < W2)
                v = *(const float4*)(actb + ((size_t)yg * W2 + xg) * C2 + ic4 * 4);
            float xs0 = v.x, xs1 = v.y, xs2 = v.z, xs3 = v.w;
            f16x4 hv, lv;
            _Float16 h;
            h = (_Float16)xs0; hv[0] = h; lv[0] = (_Float16)(xs0 - (float)h);
            h = (_Float16)xs1; hv[1] = h; lv[1] = (_Float16)(xs1 - (float)h);
            h = (_Float16)xs2; hv[2] = h; lv[2] = (_Float16)(xs2 - (float)h);
            h = (_Float16)xs3; hv[3] = h; lv[3] = (_Float16)(xs3 - (float)h);
            int kg = ic4 >> 1, h4 = ic4 & 1;
            int gr = (row * 2 + kg) * PXT + px;
            *(f16x4*)(Ah + gr * 8 + h4 * 4) = hv;
            *(f16x4*)(Al + gr * 8 + h4 * 4) = lv;
        }
    }
    __syncthreads();

    int wv = tid >> 6, lane = tid & 63;
    int col = lane & 31, half = lane >> 5;
    int y = by + wv;
    if (y >= H3) return;          // no further barriers below

    f32x16 acc[NSUB];
    #pragma unroll
    for (int s = 0; s < NSUB; ++s)
        #pragma unroll
        for (int i = 0; i < 16; ++i) acc[s][i] = 0.f;

    // per-lane weight fragment base (within-tap): [tap][kg=half][oc=col][8]
    const _Float16* wg = wbuf + (half * 32 + col) * 8;

    #pragma unroll 1
    for (int ky = 0; ky < 3; ++ky) {
        const _Float16* arh = Ah + ((wv + ky) * 2 + half) * (PXT * 8);
        const _Float16* arl = Al + ((wv + ky) * 2 + half) * (PXT * 8);
        #pragma unroll
        for (int kx = 0; kx < 3; ++kx) {
            int tap = ky * 3 + kx;
            f16x8 wh = *(const f16x8*)(wg + tap * 512);
            f16x8 wl = *(const f16x8*)(wg + 4608 + tap * 512);
            #pragma unroll
            for (int s = 0; s < NSUB; ++s) {
                int p = s * 32 + col + kx;
                f16x8 bh = *(const f16x8*)(arh + p * 8);
                f16x8 bl = *(const f16x8*)(arl + p * 8);
                acc[s] = __builtin_amdgcn_mfma_f32_32x32x16_f16(wh, bh, acc[s], 0, 0, 0);
                acc[s] = __builtin_amdgcn_mfma_f32_32x32x16_f16(wl, bh, acc[s], 0, 0, 0);
                acc[s] = __builtin_amdgcn_mfma_f32_32x32x16_f16(wh, bl, acc[s], 0, 0, 0);
            }
        }
    }

    // ---- epilogue: bias + PReLU + both heads, per lane (=per pixel) ----
    float L0[NSUB], L1[NSUB], R0[NSUB], R1[NSUB], R2[NSUB], R3[NSUB];
    #pragma unroll
    for (int s = 0; s < NSUB; ++s) { L0[s]=0.f; L1[s]=0.f; R0[s]=0.f; R1[s]=0.f; R2[s]=0.f; R3[s]=0.f; }

    #pragma unroll
    for (int r = 0; r < 16; ++r) {
        int oc = (r & 3) + 8 * (r >> 2) + 4 * half;   // verified 32x32 C-layout
        float4 t0 = *(const float4*)&htab[oc * 8];     // b3, s3, w41a, w41b
        float4 t1 = *(const float4*)&htab[oc * 8 + 4]; // w42 a..d
        #pragma unroll
        for (int s = 0; s < NSUB; ++s) {
            float v = acc[s][r] + t0.x;
            v = v > 0.f ? v : v * t0.y;
            L0[s] += v * t0.z; L1[s] += v * t0.w;
            R0[s] += v * t1.x; R1[s] += v * t1.y;
            R2[s] += v * t1.z; R3[s] += v * t1.w;
        }
    }

    float hb0 = b41[0], hb1 = b41[1];
    float rb0 = b42[0], rb1 = b42[1], rb2 = b42[2], rb3 = b42[3];

    #pragma unroll
    for (int s = 0; s < NSUB; ++s) {
        float l0 = L0[s] + __shfl_xor(L0[s], 32) + hb0;
        float l1 = L1[s] + __shfl_xor(L1[s], 32) + hb1;
        float r0 = R0[s] + __shfl_xor(R0[s], 32) + rb0;
        float r1 = R1[s] + __shfl_xor(R1[s], 32) + rb1;
        float r2 = R2[s] + __shfl_xor(R2[s], 32) + rb2;
        float r3 = R3[s] + __shfl_xor(R3[s], 32) + rb3;
        float m = fmaxf(l0, l1);
        float e0 = expf(l0 - m), e1 = expf(l1 - m);
        float p = e1 / (e0 + e1);
        int px = bx + s * 32 + col;
        if (half == 0 && px < W3) {
            size_t n = (size_t)bb * N3 + (size_t)y * W3 + px;
            scores[n] = (p >= 0.6f) ? p : NEGV;
            regf[n] = make_float4(r0, r1, r2, r3);
        }
    }
}

// ------------- kernel 4: per-image NMS (LDS-resident) + box refine -------------
__global__ __launch_bounds__(1024) void k_nms(
        const float* __restrict__ scores, const float4* __restrict__ regf,
        float* __restrict__ outp) {
    __shared__ float s_score[CAP];
    __shared__ int   s_idx[CAP];
    __shared__ float r_s[16];
    __shared__ int   r_i[16];
    __shared__ float s_picks[KP];
    __shared__ int   s_picki[KP];
    __shared__ int   s_misc[4];

    int tid = threadIdx.x;
    int bb = blockIdx.x;
    const float* sc = scores + (size_t)bb * N3;

    if (tid < 4) s_misc[tid] = 0;
    __syncthreads();

    int cnt = 0;
    for (int i = tid; i < N3; i += 1024) if (sc[i] > 0.f) cnt++;
    atomicAdd(&s_misc[0], cnt);
    __syncthreads();
    int M = s_misc[0];

    int cutbin = 0;
    if (M > CAP) {
        for (int i = tid; i < 2048; i += 1024) s_idx[i] = 0;
        __syncthreads();
        for (int i = tid; i < N3; i += 1024) {
            float s = sc[i];
            if (s > 0.f) {
                int b = (int)((s - 0.6f) * 5120.f);
                b = b < 0 ? 0 : (b > 2047 ? 2047 : b);
                atomicAdd(&s_idx[b], 1);
            }
        }
        __syncthreads();
        if (tid == 0) {
            int accum = 0, b = 2047;
            for (; b >= 0; --b) {
                int c = s_idx[b];
                if (accum + c > CAP) break;
                accum += c;
            }
            s_misc[2] = b + 1;
        }
        __syncthreads();
        cutbin = s_misc[2];
        __syncthreads();
    }

    for (int i = tid; i < N3; i += 1024) {
        float s = sc[i];
        if (s > 0.f) {
            bool keep = true;
            if (M > CAP) {
                int b = (int)((s - 0.6f) * 5120.f);
                b = b < 0 ? 0 : (b > 2047 ? 2047 : b);
                keep = (b >= cutbin);
            }
            if (keep) {
                int pos = atomicAdd(&s_misc[1], 1);
                if (pos < CAP) { s_score[pos] = s; s_idx[pos] = i; }
            }
        }
    }
    __syncthreads();
    int M2 = s_misc[1]; if (M2 > CAP) M2 = CAP;

    int np = 0;
    for (int pick = 0; pick < KP; ++pick) {
        float bs = -INFINITY; int bi = 0x7fffffff;
        for (int i = tid; i < M2; i += 1024) {
            float s = s_score[i]; int id = s_idx[i];
            if (s > bs || (s == bs && id < bi)) { bs = s; bi = id; }
        }
        #pragma unroll
        for (int off = 32; off; off >>= 1) {
            float os = __shfl_down(bs, off);
            int   oi = __shfl_down(bi, off);
            if (os > bs || (os == bs && oi < bi)) { bs = os; bi = oi; }
        }
        int lane = tid & 63, wv = tid >> 6;
        if (lane == 0) { r_s[wv] = bs; r_i[wv] = bi; }
        __syncthreads();
        if (tid == 0) {
            float ps = r_s[0]; int pi = r_i[0];
            for (int k = 1; k < 16; ++k) {
                float os = r_s[k]; int oi = r_i[k];
                if (os > ps || (os == ps && oi < pi)) { ps = os; pi = oi; }
            }
            s_picks[pick] = ps; s_picki[pick] = pi;
            r_s[0] = ps; r_i[0] = pi;
        }
        __syncthreads();
        float ps = r_s[0]; int pi = r_i[0];
        if (ps < 0.f) break;
        np = pick + 1;

        int pcx = pi % W3, pcy = pi / W3;
        float px1 = (float)(2 * pcx + 1), py1 = (float)(2 * pcy + 1);
        float px2 = (float)(2 * pcx + 12), py2 = (float)(2 * pcy + 12);
        for (int i = tid; i < M2; i += 1024) {
            float s = s_score[i];
            if (s > NEGV * 0.5f) {
                int id = s_idx[i];
                int cx = id % W3, cy = id / W3;
                float x1 = (float)(2 * cx + 1), y1 = (float)(2 * cy + 1);
                float x2 = (float)(2 * cx + 12), y2 = (float)(2 * cy + 12);
                float xx1 = fmaxf(px1, x1), yy1 = fmaxf(py1, y1);
                float xx2 = fminf(px2, x2), yy2 = fminf(py2, y2);
                float inter = fmaxf(0.f, xx2 - xx1 + 1.f) * fmaxf(0.f, yy2 - yy1 + 1.f);
                float iou = inter / (288.f - inter);
                if (iou > 0.5f) s_score[i] = NEGV;
            }
        }
        __syncthreads();
    }

    if (tid < KP) {
        float* o = outp + ((size_t)bb * KP + tid) * 5;
        if (tid < np) {
            int pi = s_picki[tid]; float ps = s_picks[tid];
            int cx = pi % W3, cy = pi / W3;
            float x1 = (float)(2 * cx + 1), y1 = (float)(2 * cy + 1);
            float x2 = (float)(2 * cx + 12), y2 = (float)(2 * cy + 12);
            float4 r = regf[(size_t)bb * N3 + pi];
            float wd = x2 - x1, hh = y2 - y1;
            float q1 = x1 + r.x * wd, q2 = y1 + r.y * hh;
            float q3 = x2 + r.z * wd, q4 = y2 + r.w * hh;
            float rw = q3 - q1, rh = q4 - q2;
            float L = fmaxf(rw, rh);
            float nx1 = q1 + rw * 0.5f - L * 0.5f;
            float ny1 = q2 + rh * 0.5f - L * 0.5f;
            o[0] = nx1; o[1] = ny1; o[2] = nx1 + L; o[3] = ny1 + L; o[4] = ps;
        } else {
            o[0] = 0.f; o[1] = 0.f; o[2] = 0.f; o[3] = 0.f; o[4] = 0.f;
        }
    }
}

// ---------------- launcher ----------------
extern "C" void kernel_launch(void* const* d_in, const int* in_sizes, int n_in,
                              void* d_out, int out_size, void* d_ws, size_t ws_size,
                              hipStream_t stream) {
    const float* im   = (const float*)d_in[0];
    const float* c1w  = (const float*)d_in[1];
    const float* c1b  = (const float*)d_in[2];
    const float* p1   = (const float*)d_in[3];
    const float* c2w  = (const float*)d_in[4];
    const float* c2b  = (const float*)d_in[5];
    const float* p2   = (const float*)d_in[6];
    const float* c3w  = (const float*)d_in[7];
    const float* c3b  = (const float*)d_in[8];
    const float* p3   = (const float*)d_in[9];
    const float* c41w = (const float*)d_in[10];
    const float* c41b = (const float*)d_in[11];
    const float* c42w = (const float*)d_in[12];
    const float* c42b = (const float*)d_in[13];

    float* ws = (float*)d_ws;
    const size_t POOL1_FLOATS = (size_t)BATCH * C1 * P1H * P1W;   // 7,792,800
    float*  pool1  = ws;
    float*  conv2b = ws + POOL1_FLOATS;                          // NHWC
    float*  scoresb = ws;                                        // reuse region0
    float4* regfb   = (float4*)(ws + (size_t)BATCH * N3);        // 16B-aligned
    // weight hi/lo scratch: d_out (40960B >= 18432B); k_nms overwrites it at the end
    _Float16* wbuf = (_Float16*)d_out;

    k_conv1pool<<<dim3(16, 12, BATCH), dim3(16, 16), 0, stream>>>(im, c1w, c1b, p1, pool1,
                                                                  c3w, wbuf);
    k_conv2   <<<dim3(2, 48, BATCH), dim3(64, 4), 0, stream>>>(pool1, c2w, c2b, p2, conv2b);
    k_conv3mfma<<<dim3(3, 47, BATCH), dim3(256), 0, stream>>>(conv2b, wbuf, c3b, p3,
                                                              c41w, c41b, c42w, c42b,
                                                              scoresb, regfb);
    k_nms<<<dim3(BATCH), dim3(1024), 0, stream>>>(scoresb, regfb, (float*)d_out);
}

// Round 4
// 223.692 us; speedup vs baseline: 1.2858x; 1.2858x over previous
//
#include <hip/hip_runtime.h>
#include <math.h>

// ---------------- problem constants ----------------
#define BATCH 16
#define IH 384
#define IW 512
#define C1 10
#define P1H 191   // pooled H after conv1(382) / 2
#define P1W 255   // pooled W after conv1(510) / 2
#define C2 16
#define H2 189
#define W2 253
#define C3 32
#define H3 187
#define W3 251
#define N3 (H3*W3)        // 46937
#define KP 128
#define CAP 7680          // max candidates kept for NMS (LDS-resident)
#define NEGV (-1e30f)

typedef _Float16 f16x8 __attribute__((ext_vector_type(8)));
typedef _Float16 f16x4 __attribute__((ext_vector_type(4)));
typedef float    f32x16 __attribute__((ext_vector_type(16)));

#define PXT 66            // staged px per block: 64 computed + 2 halo
#define NSUB 2            // 2 x 32-px MFMA sub-tiles per wave (acc = 32 regs)

// ------------- kernel 1: conv1(3->10,3x3) + PReLU + maxpool2 -------------
// block (0,0,0) additionally pre-splits conv3 weights into f16 hi/lo planes
// (layout [tap][kgroup][oc][8ic]) -- saves a separate dispatch.
__global__ __launch_bounds__(256, 2) void k_conv1pool(
        const float* __restrict__ im, const float* __restrict__ w,
        const float* __restrict__ bia, const float* __restrict__ slope,
        float* __restrict__ outp,
        const float* __restrict__ w3, _Float16* __restrict__ wbuf) {
    if (blockIdx.x == 0 && blockIdx.y == 0 && blockIdx.z == 0) {
        int tid = threadIdx.y * 16 + threadIdx.x;
        for (int e = tid; e < 4608; e += 256) {
            int oc = e / 144;
            int rem = e - oc * 144;
            int ic = rem / 9;
            int tap = rem - ic * 9;
            float v = w3[e];                   // [oc][ic][ky][kx] natural order
            _Float16 h = (_Float16)v;
            _Float16 l = (_Float16)(v - (float)h);
            int d = ((tap * 2 + (ic >> 3)) * 32 + oc) * 8 + (ic & 7);
            wbuf[d] = h;
            wbuf[4608 + d] = l;
        }
    }

    int x = blockIdx.x * 16 + threadIdx.x;
    int y = blockIdx.y * 16 + threadIdx.y;
    int bb = blockIdx.z;
    if (x >= P1W || y >= P1H) return;

    float in[3][4][4];
    #pragma unroll
    for (int ci = 0; ci < 3; ++ci) {
        const float* p = im + (((size_t)bb * 3 + ci) * IH + 2 * y) * IW + 2 * x;
        #pragma unroll
        for (int r = 0; r < 4; ++r) {
            const float2* q = (const float2*)(p + (size_t)r * IW);
            float2 a0 = q[0], a1 = q[1];
            in[ci][r][0] = a0.x; in[ci][r][1] = a0.y;
            in[ci][r][2] = a1.x; in[ci][r][3] = a1.y;
        }
    }
    #pragma unroll
    for (int ci = 0; ci < 3; ++ci)
        #pragma unroll
        for (int r = 0; r < 4; ++r)
            #pragma unroll
            for (int c = 0; c < 4; ++c)
                in[ci][r][c] = (in[ci][r][c] - 127.5f) * 0.0078125f;

    #pragma unroll
    for (int oc = 0; oc < C1; ++oc) {
        const float* wo = w + oc * 27;
        float bv = bia[oc], sv = slope[oc];
        float best = -INFINITY;
        #pragma unroll
        for (int py = 0; py < 2; ++py)
            #pragma unroll
            for (int px = 0; px < 2; ++px) {
                float acc = bv;
                #pragma unroll
                for (int ci = 0; ci < 3; ++ci)
                    #pragma unroll
                    for (int ky = 0; ky < 3; ++ky)
                        #pragma unroll
                        for (int kx = 0; kx < 3; ++kx)
                            acc += in[ci][py + ky][px + kx] * wo[(ci * 3 + ky) * 3 + kx];
                float v = acc > 0.f ? acc : sv * acc;
                best = fmaxf(best, v);
            }
        outp[(((size_t)bb * C1 + oc) * P1H + y) * P1W + x] = best;
    }
}

// ------------- kernel 2: conv2(10->16,3x3) + PReLU, NHWC output -------------
// Per-thread NHWC data (2px x 16ch = 128B contiguous per thread) is re-staged
// through a 32KB XOR-swizzled LDS buffer so global stores are fully coalesced
// float4s. Swizzle phys = g ^ ((g>>3)&7) is conflict-free on both sides.
__global__ __launch_bounds__(256, 2) void k_conv2(
        const float* __restrict__ inp, const float* __restrict__ w,
        const float* __restrict__ bia, const float* __restrict__ slope,
        float* __restrict__ outp) {
    __shared__ float4 sbuf[2048];          // [4 rows][128 px][4 c4] granules
    int tx = threadIdx.x, ty = threadIdx.y;
    int tid = ty * 64 + tx;
    int x0 = blockIdx.x * 128 + tx * 2;
    int y  = blockIdx.y * 4 + ty;
    int bb = blockIdx.z;
    bool alive = (x0 < W2) && (y < H2);

    float a0[C2], a1[C2];
    #pragma unroll
    for (int oc = 0; oc < C2; ++oc) { a0[oc] = bia[oc]; a1[oc] = bia[oc]; }

    if (alive) {
        bool tail = (x0 + 3 > P1W - 1);
        for (int ci = 0; ci < C1; ++ci) {
            const float* p = inp + (((size_t)bb * C1 + ci) * P1H + y) * P1W + x0;
            float v[3][4];
            #pragma unroll
            for (int r = 0; r < 3; ++r) {
                const float* pr = p + (size_t)r * P1W;
                v[r][0] = pr[0]; v[r][1] = pr[1]; v[r][2] = pr[2];
                v[r][3] = tail ? 0.f : pr[3];
            }
            const float* wc = w + ci * 9;
            #pragma unroll
            for (int oc = 0; oc < C2; ++oc) {
                const float* wo = wc + oc * (C1 * 9);
                float s0 = a0[oc], s1 = a1[oc];
                #pragma unroll
                for (int ky = 0; ky < 3; ++ky)
                    #pragma unroll
                    for (int kx = 0; kx < 3; ++kx) {
                        float wv = wo[ky * 3 + kx];
                        s0 += v[ky][kx]     * wv;
                        s1 += v[ky][kx + 1] * wv;
                    }
                a0[oc] = s0; a1[oc] = s1;
            }
        }
        #pragma unroll
        for (int oc = 0; oc < C2; ++oc) {
            float sl = slope[oc];
            float u0 = a0[oc]; a0[oc] = u0 > 0.f ? u0 : sl * u0;
            float u1 = a1[oc]; a1[oc] = u1 > 0.f ? u1 : sl * u1;
        }
    }

    // stage to LDS (swizzled, conflict-free: 8 consecutive lanes hit 8 groups)
    #pragma unroll
    for (int c4 = 0; c4 < 4; ++c4) {
        int g0 = tid * 8 + c4;
        int p0 = g0 ^ ((g0 >> 3) & 7);
        sbuf[p0] = make_float4(a0[c4 * 4], a0[c4 * 4 + 1], a0[c4 * 4 + 2], a0[c4 * 4 + 3]);
        int g1 = tid * 8 + 4 + c4;
        int p1 = g1 ^ ((g1 >> 3) & 7);
        sbuf[p1] = make_float4(a1[c4 * 4], a1[c4 * 4 + 1], a1[c4 * 4 + 2], a1[c4 * 4 + 3]);
    }
    __syncthreads();

    // coalesced copy-out: consecutive lanes -> consecutive float4s
    const size_t obase = (size_t)bb * H2 * W2 * C2;
    #pragma unroll
    for (int it = 0; it < 8; ++it) {
        int g = it * 256 + tid;
        int c4 = g & 3, px = (g >> 2) & 127, ry = g >> 9;
        int xg = blockIdx.x * 128 + px, yg = blockIdx.y * 4 + ry;
        if (xg < W2 && yg < H2) {
            int phys = g ^ ((g >> 3) & 7);
            *(float4*)(outp + obase + ((size_t)yg * W2 + xg) * C2 + c4 * 4) = sbuf[phys];
        }
    }
}

// ------------- kernel 3: conv3 via MFMA (f16x2 split) + heads -------------
// Round-3 changes (unchanged on retry; round-3 bench was an infra failure):
//  * NSUB 3 -> 2 (64-px tile): acc 48 -> 32 regs; total reg need ~100-110 so
//    the allocator lands in the <=128 bucket -> 4 waves/SIMD WITHOUT forcing
//    a cap. launch_bounds(256,2) = safe cap (round 2's (256,4) split the
//    unified file 64+64 and spilled acc -> 350MB/dispatch scratch traffic).
//  * keeps round-2's conflict-free A layout [row][kg][px] 16B granules and
//    L1-resident global weight fragments (no weight LDS). LDS = 26.4 KB.
__global__ __launch_bounds__(256, 2) void k_conv3mfma(
        const float* __restrict__ act,            // conv2 output, NHWC
        const _Float16* __restrict__ wbuf,        // pre-split weights hi|lo
        const float* __restrict__ b3, const float* __restrict__ s3,
        const float* __restrict__ w41, const float* __restrict__ b41,
        const float* __restrict__ w42, const float* __restrict__ b42,
        float* __restrict__ scores, float4* __restrict__ regf) {
    __shared__ __align__(16) _Float16 Ah[6 * 2 * PXT * 8];  // 12672 B
    __shared__ __align__(16) _Float16 Al[6 * 2 * PXT * 8];  // 12672 B
    __shared__ __align__(16) float    htab[32 * 8];          // 1024 B (26.4KB tot)

    int tid = threadIdx.x;
    int bx = blockIdx.x * (NSUB * 32);
    int by = blockIdx.y * 4;
    int bb = blockIdx.z;

    // -- stage per-oc head table: b3, s3, w41[0], w41[1], w42[0..3] --
    {
        int oc = tid >> 3, f = tid & 7;
        float v;
        if      (f == 0) v = b3[oc];
        else if (f == 1) v = s3[oc];
        else if (f == 2) v = w41[oc];
        else if (f == 3) v = w41[32 + oc];
        else             v = w42[(f - 4) * 32 + oc];
        htab[tid] = v;
    }
    // -- stage activations: NHWC global -> LDS [row][kg][px] granules, hi/lo --
    {
        const float* actb = act + (size_t)bb * H2 * W2 * C2;
        for (int e = tid; e < 6 * PXT * 4; e += 256) {
            int ic4 = e & 3;
            int t = e >> 2;
            int px = t % PXT;
            int row = t / PXT;
            int yg = by + row, xg = bx + px;
            float4 v = make_float4(0.f, 0.f, 0.f, 0.f);
            if (yg < H2 && xg < W2)
                v = *(const float4*)(actb + ((size_t)yg * W2 + xg) * C2 + ic4 * 4);
            float xs0 = v.x, xs1 = v.y, xs2 = v.z, xs3 = v.w;
            f16x4 hv, lv;
            _Float16 h;
            h = (_Float16)xs0; hv[0] = h; lv[0] = (_Float16)(xs0 - (float)h);
            h = (_Float16)xs1; hv[1] = h; lv[1] = (_Float16)(xs1 - (float)h);
            h = (_Float16)xs2; hv[2] = h; lv[2] = (_Float16)(xs2 - (float)h);
            h = (_Float16)xs3; hv[3] = h; lv[3] = (_Float16)(xs3 - (float)h);
            int kg = ic4 >> 1, h4 = ic4 & 1;
            int gr = (row * 2 + kg) * PXT + px;
            *(f16x4*)(Ah + gr * 8 + h4 * 4) = hv;
            *(f16x4*)(Al + gr * 8 + h4 * 4) = lv;
        }
    }
    __syncthreads();

    int wv = tid >> 6, lane = tid & 63;
    int col = lane & 31, half = lane >> 5;
    int y = by + wv;
    if (y >= H3) return;          // no further barriers below

    f32x16 acc[NSUB];
    #pragma unroll
    for (int s = 0; s < NSUB; ++s)
        #pragma unroll
        for (int i = 0; i < 16; ++i) acc[s][i] = 0.f;

    // per-lane weight fragment base (within-tap): [tap][kg=half][oc=col][8]
    const _Float16* wg = wbuf + (half * 32 + col) * 8;

    #pragma unroll 1
    for (int ky = 0; ky < 3; ++ky) {
        const _Float16* arh = Ah + ((wv + ky) * 2 + half) * (PXT * 8);
        const _Float16* arl = Al + ((wv + ky) * 2 + half) * (PXT * 8);
        #pragma unroll
        for (int kx = 0; kx < 3; ++kx) {
            int tap = ky * 3 + kx;
            f16x8 wh = *(const f16x8*)(wg + tap * 512);
            f16x8 wl = *(const f16x8*)(wg + 4608 + tap * 512);
            #pragma unroll
            for (int s = 0; s < NSUB; ++s) {
                int p = s * 32 + col + kx;
                f16x8 bh = *(const f16x8*)(arh + p * 8);
                f16x8 bl = *(const f16x8*)(arl + p * 8);
                acc[s] = __builtin_amdgcn_mfma_f32_32x32x16_f16(wh, bh, acc[s], 0, 0, 0);
                acc[s] = __builtin_amdgcn_mfma_f32_32x32x16_f16(wl, bh, acc[s], 0, 0, 0);
                acc[s] = __builtin_amdgcn_mfma_f32_32x32x16_f16(wh, bl, acc[s], 0, 0, 0);
            }
        }
    }

    // ---- epilogue: bias + PReLU + both heads, per lane (=per pixel) ----
    float L0[NSUB], L1[NSUB], R0[NSUB], R1[NSUB], R2[NSUB], R3[NSUB];
    #pragma unroll
    for (int s = 0; s < NSUB; ++s) { L0[s]=0.f; L1[s]=0.f; R0[s]=0.f; R1[s]=0.f; R2[s]=0.f; R3[s]=0.f; }

    #pragma unroll
    for (int r = 0; r < 16; ++r) {
        int oc = (r & 3) + 8 * (r >> 2) + 4 * half;   // verified 32x32 C-layout
        float4 t0 = *(const float4*)&htab[oc * 8];     // b3, s3, w41a, w41b
        float4 t1 = *(const float4*)&htab[oc * 8 + 4]; // w42 a..d
        #pragma unroll
        for (int s = 0; s < NSUB; ++s) {
            float v = acc[s][r] + t0.x;
            v = v > 0.f ? v : v * t0.y;
            L0[s] += v * t0.z; L1[s] += v * t0.w;
            R0[s] += v * t1.x; R1[s] += v * t1.y;
            R2[s] += v * t1.z; R3[s] += v * t1.w;
        }
    }

    float hb0 = b41[0], hb1 = b41[1];
    float rb0 = b42[0], rb1 = b42[1], rb2 = b42[2], rb3 = b42[3];

    #pragma unroll
    for (int s = 0; s < NSUB; ++s) {
        float l0 = L0[s] + __shfl_xor(L0[s], 32) + hb0;
        float l1 = L1[s] + __shfl_xor(L1[s], 32) + hb1;
        float r0 = R0[s] + __shfl_xor(R0[s], 32) + rb0;
        float r1 = R1[s] + __shfl_xor(R1[s], 32) + rb1;
        float r2 = R2[s] + __shfl_xor(R2[s], 32) + rb2;
        float r3 = R3[s] + __shfl_xor(R3[s], 32) + rb3;
        float m = fmaxf(l0, l1);
        float e0 = expf(l0 - m), e1 = expf(l1 - m);
        float p = e1 / (e0 + e1);
        int px = bx + s * 32 + col;
        if (half == 0 && px < W3) {
            size_t n = (size_t)bb * N3 + (size_t)y * W3 + px;
            scores[n] = (p >= 0.6f) ? p : NEGV;
            regf[n] = make_float4(r0, r1, r2, r3);
        }
    }
}

// ------------- kernel 4: per-image NMS (LDS-resident) + box refine -------------
__global__ __launch_bounds__(1024) void k_nms(
        const float* __restrict__ scores, const float4* __restrict__ regf,
        float* __restrict__ outp) {
    __shared__ float s_score[CAP];
    __shared__ int   s_idx[CAP];
    __shared__ float r_s[16];
    __shared__ int   r_i[16];
    __shared__ float s_picks[KP];
    __shared__ int   s_picki[KP];
    __shared__ int   s_misc[4];

    int tid = threadIdx.x;
    int bb = blockIdx.x;
    const float* sc = scores + (size_t)bb * N3;

    if (tid < 4) s_misc[tid] = 0;
    __syncthreads();

    int cnt = 0;
    for (int i = tid; i < N3; i += 1024) if (sc[i] > 0.f) cnt++;
    atomicAdd(&s_misc[0], cnt);
    __syncthreads();
    int M = s_misc[0];

    int cutbin = 0;
    if (M > CAP) {
        for (int i = tid; i < 2048; i += 1024) s_idx[i] = 0;
        __syncthreads();
        for (int i = tid; i < N3; i += 1024) {
            float s = sc[i];
            if (s > 0.f) {
                int b = (int)((s - 0.6f) * 5120.f);
                b = b < 0 ? 0 : (b > 2047 ? 2047 : b);
                atomicAdd(&s_idx[b], 1);
            }
        }
        __syncthreads();
        if (tid == 0) {
            int accum = 0, b = 2047;
            for (; b >= 0; --b) {
                int c = s_idx[b];
                if (accum + c > CAP) break;
                accum += c;
            }
            s_misc[2] = b + 1;
        }
        __syncthreads();
        cutbin = s_misc[2];
        __syncthreads();
    }

    for (int i = tid; i < N3; i += 1024) {
        float s = sc[i];
        if (s > 0.f) {
            bool keep = true;
            if (M > CAP) {
                int b = (int)((s - 0.6f) * 5120.f);
                b = b < 0 ? 0 : (b > 2047 ? 2047 : b);
                keep = (b >= cutbin);
            }
            if (keep) {
                int pos = atomicAdd(&s_misc[1], 1);
                if (pos < CAP) { s_score[pos] = s; s_idx[pos] = i; }
            }
        }
    }
    __syncthreads();
    int M2 = s_misc[1]; if (M2 > CAP) M2 = CAP;

    int np = 0;
    for (int pick = 0; pick < KP; ++pick) {
        float bs = -INFINITY; int bi = 0x7fffffff;
        for (int i = tid; i < M2; i += 1024) {
            float s = s_score[i]; int id = s_idx[i];
            if (s > bs || (s == bs && id < bi)) { bs = s; bi = id; }
        }
        #pragma unroll
        for (int off = 32; off; off >>= 1) {
            float os = __shfl_down(bs, off);
            int   oi = __shfl_down(bi, off);
            if (os > bs || (os == bs && oi < bi)) { bs = os; bi = oi; }
        }
        int lane = tid & 63, wv = tid >> 6;
        if (lane == 0) { r_s[wv] = bs; r_i[wv] = bi; }
        __syncthreads();
        if (tid == 0) {
            float ps = r_s[0]; int pi = r_i[0];
            for (int k = 1; k < 16; ++k) {
                float os = r_s[k]; int oi = r_i[k];
                if (os > ps || (os == ps && oi < pi)) { ps = os; pi = oi; }
            }
            s_picks[pick] = ps; s_picki[pick] = pi;
            r_s[0] = ps; r_i[0] = pi;
        }
        __syncthreads();
        float ps = r_s[0]; int pi = r_i[0];
        if (ps < 0.f) break;
        np = pick + 1;

        int pcx = pi % W3, pcy = pi / W3;
        float px1 = (float)(2 * pcx + 1), py1 = (float)(2 * pcy + 1);
        float px2 = (float)(2 * pcx + 12), py2 = (float)(2 * pcy + 12);
        for (int i = tid; i < M2; i += 1024) {
            float s = s_score[i];
            if (s > NEGV * 0.5f) {
                int id = s_idx[i];
                int cx = id % W3, cy = id / W3;
                float x1 = (float)(2 * cx + 1), y1 = (float)(2 * cy + 1);
                float x2 = (float)(2 * cx + 12), y2 = (float)(2 * cy + 12);
                float xx1 = fmaxf(px1, x1), yy1 = fmaxf(py1, y1);
                float xx2 = fminf(px2, x2), yy2 = fminf(py2, y2);
                float inter = fmaxf(0.f, xx2 - xx1 + 1.f) * fmaxf(0.f, yy2 - yy1 + 1.f);
                float iou = inter / (288.f - inter);
                if (iou > 0.5f) s_score[i] = NEGV;
            }
        }
        __syncthreads();
    }

    if (tid < KP) {
        float* o = outp + ((size_t)bb * KP + tid) * 5;
        if (tid < np) {
            int pi = s_picki[tid]; float ps = s_picks[tid];
            int cx = pi % W3, cy = pi / W3;
            float x1 = (float)(2 * cx + 1), y1 = (float)(2 * cy + 1);
            float x2 = (float)(2 * cx + 12), y2 = (float)(2 * cy + 12);
            float4 r = regf[(size_t)bb * N3 + pi];
            float wd = x2 - x1, hh = y2 - y1;
            float q1 = x1 + r.x * wd, q2 = y1 + r.y * hh;
            float q3 = x2 + r.z * wd, q4 = y2 + r.w * hh;
            float rw = q3 - q1, rh = q4 - q2;
            float L = fmaxf(rw, rh);
            float nx1 = q1 + rw * 0.5f - L * 0.5f;
            float ny1 = q2 + rh * 0.5f - L * 0.5f;
            o[0] = nx1; o[1] = ny1; o[2] = nx1 + L; o[3] = ny1 + L; o[4] = ps;
        } else {
            o[0] = 0.f; o[1] = 0.f; o[2] = 0.f; o[3] = 0.f; o[4] = 0.f;
        }
    }
}

// ---------------- launcher ----------------
extern "C" void kernel_launch(void* const* d_in, const int* in_sizes, int n_in,
                              void* d_out, int out_size, void* d_ws, size_t ws_size,
                              hipStream_t stream) {
    const float* im   = (const float*)d_in[0];
    const float* c1w  = (const float*)d_in[1];
    const float* c1b  = (const float*)d_in[2];
    const float* p1   = (const float*)d_in[3];
    const float* c2w  = (const float*)d_in[4];
    const float* c2b  = (const float*)d_in[5];
    const float* p2   = (const float*)d_in[6];
    const float* c3w  = (const float*)d_in[7];
    const float* c3b  = (const float*)d_in[8];
    const float* p3   = (const float*)d_in[9];
    const float* c41w = (const float*)d_in[10];
    const float* c41b = (const float*)d_in[11];
    const float* c42w = (const float*)d_in[12];
    const float* c42b = (const float*)d_in[13];

    float* ws = (float*)d_ws;
    const size_t POOL1_FLOATS = (size_t)BATCH * C1 * P1H * P1W;   // 7,792,800
    float*  pool1  = ws;
    float*  conv2b = ws + POOL1_FLOATS;                          // NHWC
    float*  scoresb = ws;                                        // reuse region0
    float4* regfb   = (float4*)(ws + (size_t)BATCH * N3);        // 16B-aligned
    // weight hi/lo scratch: d_out (40960B >= 18432B); k_nms overwrites it at the end
    _Float16* wbuf = (_Float16*)d_out;

    k_conv1pool<<<dim3(16, 12, BATCH), dim3(16, 16), 0, stream>>>(im, c1w, c1b, p1, pool1,
                                                                  c3w, wbuf);
    k_conv2   <<<dim3(2, 48, BATCH), dim3(64, 4), 0, stream>>>(pool1, c2w, c2b, p2, conv2b);
    k_conv3mfma<<<dim3(4, 47, BATCH), dim3(256), 0, stream>>>(conv2b, wbuf, c3b, p3,
                                                              c41w, c41b, c42w, c42b,
                                                              scoresb, regfb);
    k_nms<<<dim3(BATCH), dim3(1024), 0, stream>>>(scoresb, regfb, (float*)d_out);
}